// Round 8
// baseline (94.973 us; speedup 1.0000x reference)
//
#include <hip/hip_runtime.h>
#include <hip/hip_bf16.h>
#include <math.h>

#define N 8192
#define D 128
#define MARGIN_V 0.3f
#define NEG_FILL 1000000.0f

typedef short bf16x8 __attribute__((ext_vector_type(8)));
typedef float f32x4  __attribute__((ext_vector_type(4)));

__device__ __forceinline__ void g2l16(const void* g, void* l) {
    __builtin_amdgcn_global_load_lds(
        (const __attribute__((address_space(1))) void*)g,
        (__attribute__((address_space(3))) void*)l, 16, 0, 0);
}

// ---------- convert: F fp32 -> bf16, sq[i] = ||f_i||^2; init ap/an ----------
__global__ __launch_bounds__(256) void convert_kernel(const float* __restrict__ F,
                                                      unsigned short* __restrict__ Fb,
                                                      float* __restrict__ sq,
                                                      unsigned* __restrict__ ap,
                                                      unsigned* __restrict__ an) {
    int row  = blockIdx.x * 4 + (threadIdx.x >> 6);
    int lane = threadIdx.x & 63;
    float2 v = *(const float2*)&F[row * D + lane * 2];
    float s = v.x * v.x + v.y * v.y;
    __hip_bfloat162 t = __float22bfloat162_rn(v);
    *(unsigned int*)&Fb[row * D + lane * 2] = *(unsigned int*)&t;
    #pragma unroll
    for (int off = 32; off >= 1; off >>= 1) s += __shfl_xor(s, off);
    if (lane == 0) sq[row] = s;
    int gid = blockIdx.x * 256 + threadIdx.x;
    if (gid < N) { ap[gid] = 0u; an[gid] = 0x7F800000u; }   // 0.0f / +inf (d^2 domain)
}

// ---------- gemm: triangular strips, dual (row+col) mining ----------
// Block = (strip s: 128 rows) x (chunk c: 512 cols), launched only where the
// chunk has tiles jt >= 2s (544 blocks). Tiles t = t0..7 (64 cols each).
// Each pair computed once; mined for its row (registers) and its column
// (quad-shuffle + LDS accumulator in the reused A-staging region).
// Mining directly in d^2 domain; clamp deferred (max/min commute with clamp).
__global__ __launch_bounds__(256, 2) void gemm_kernel(const unsigned short* __restrict__ Fb,
                                                      const float* __restrict__ sq,
                                                      const int* __restrict__ lab,
                                                      unsigned* __restrict__ ap,
                                                      unsigned* __restrict__ an) {
    __shared__ __align__(16) unsigned short As[128 * 128];    // 32 KB; reused as colAcc
    __shared__ __align__(16) unsigned short Bs[2][64 * 128];  // 2 x 16 KB
    __shared__ float sqj_s[512];
    __shared__ int   labj_s[512];
    __shared__ float sqi_s[128];
    __shared__ int   labi_s[128];

    // ---- decode blockIdx -> (s, c); c >= floor(s/4); 544 blocks total ----
    int k = blockIdx.x;
    int s = 0, cum = 0;
    while (true) { int cnt = 16 - (s >> 2); if (k < cum + cnt) break; cum += cnt; ++s; }
    int c = (s >> 2) + (k - cum);
    int t0 = 2 * s - 8 * c; if (t0 < 0) t0 = 0;   // always even, <= 6

    const int i0 = s * 128, j0 = c * 512;
    const int tid  = threadIdx.x;
    const int wave = tid >> 6, lane = tid & 63;
    const int wy = wave >> 1, wx = wave & 1;   // wave = 64 rows (wy) x 32 cols (wx)
    const int quad = lane >> 4, lr = lane & 15;

    // stage metadata
    {
        float2 v = *(const float2*)&sq[j0 + tid * 2];
        sqj_s[tid * 2] = v.x; sqj_s[tid * 2 + 1] = v.y;
        int2 w = *(const int2*)&lab[j0 + tid * 2];
        labj_s[tid * 2] = w.x; labj_s[tid * 2 + 1] = w.y;
    }
    if (tid < 128) { sqi_s[tid] = sq[i0 + tid]; labi_s[tid] = lab[i0 + tid]; }

    // stage A tile (128 x 128 k), XOR-swizzled chunks
    #pragma unroll
    for (int it = 0; it < 8; ++it) {
        int c_id = it * 256 + tid;
        int row = c_id >> 4, p = c_id & 15;
        int sc = (p & 8) | ((p ^ row) & 7);
        g2l16(Fb + (size_t)(i0 + row) * D + sc * 8, (char*)As + c_id * 16);
    }
    // stage B tile t0 (t0 even -> Bs[0])
    #pragma unroll
    for (int it = 0; it < 4; ++it) {
        int c_id = it * 256 + tid;
        int row = c_id >> 4, p = c_id & 15;
        int sc = (p & 8) | ((p ^ row) & 7);
        g2l16(Fb + (size_t)(j0 + t0 * 64 + row) * D + sc * 8, (char*)&Bs[0][0] + c_id * 16);
    }
    __syncthreads();

    // A fragments -> registers (4 row-frags x 4 k-blocks)
    bf16x8 af[4][4];
    #pragma unroll
    for (int a = 0; a < 4; ++a)
        #pragma unroll
        for (int ks = 0; ks < 4; ++ks) {
            int row = wy * 64 + a * 16 + lr;
            int kc  = ks * 4 + quad;
            int pos = (kc & 8) | ((kc ^ row) & 7);
            af[a][ks] = *(const bf16x8*)&As[row * 128 + pos * 8];
        }
    f32x4 sqi4[4]; int4 labi4[4];
    #pragma unroll
    for (int a = 0; a < 4; ++a) {
        int base = wy * 64 + a * 16 + quad * 4;
        sqi4[a]  = *(const f32x4*)&sqi_s[base];
        labi4[a] = *(const int4*)&labi_s[base];
    }
    __syncthreads();   // all As reads done -> reuse As region as colAcc

    float* colP_s = (float*)As;          // [2 wy][512 cols]
    float* colN_s = (float*)As + 1024;
    ((f32x4*)colP_s)[tid] = {-INFINITY, -INFINITY, -INFINITY, -INFINITY};
    ((f32x4*)colN_s)[tid] = { INFINITY,  INFINITY,  INFINITY,  INFINITY};

    float rowP[4][4], rowN[4][4];
    #pragma unroll
    for (int a = 0; a < 4; ++a)
        #pragma unroll
        for (int r = 0; r < 4; ++r) { rowP[a][r] = -INFINITY; rowN[a][r] = INFINITY; }

    #pragma unroll 1
    for (int t = t0; t < 8; ++t) {
        // prefetch next B tile
        if (t < 7) {
            #pragma unroll
            for (int it = 0; it < 4; ++it) {
                int c_id = it * 256 + tid;
                int row = c_id >> 4, p = c_id & 15;
                int sc = (p & 8) | ((p ^ row) & 7);
                g2l16(Fb + (size_t)(j0 + (t + 1) * 64 + row) * D + sc * 8,
                      (char*)&Bs[(t + 1) & 1][0] + c_id * 16);
            }
        }
        float sqj_l[2]; int labj_l[2];
        #pragma unroll
        for (int b = 0; b < 2; ++b) {
            int cl = (t << 6) + wx * 32 + b * 16 + lr;
            sqj_l[b]  = sqj_s[cl];
            labj_l[b] = labj_s[cl];
        }
        f32x4 acc[4][2];
        #pragma unroll
        for (int a = 0; a < 4; ++a)
            #pragma unroll
            for (int b = 0; b < 2; ++b) acc[a][b] = {0.f, 0.f, 0.f, 0.f};
        #pragma unroll
        for (int ks = 0; ks < 4; ++ks) {
            bf16x8 bfr[2];
            #pragma unroll
            for (int b = 0; b < 2; ++b) {
                int rb  = wx * 32 + b * 16 + lr;
                int kc  = ks * 4 + quad;
                int pos = (kc & 8) | ((kc ^ rb) & 7);
                bfr[b] = *(const bf16x8*)&Bs[t & 1][rb * 128 + pos * 8];
            }
            #pragma unroll
            for (int a = 0; a < 4; ++a)
                #pragma unroll
                for (int b = 0; b < 2; ++b)
                    acc[a][b] = __builtin_amdgcn_mfma_f32_16x16x32_bf16(af[a][ks], bfr[b], acc[a][b], 0, 0, 0);
        }
        __syncthreads();   // Bs[t&1] reads done; prefetch drained

        // dual mining epilogue, d^2 domain
        float colP[2] = {-INFINITY, -INFINITY}, colN[2] = {INFINITY, INFINITY};
        #pragma unroll
        for (int a = 0; a < 4; ++a)
            #pragma unroll
            for (int b = 0; b < 2; ++b)
                #pragma unroll
                for (int r = 0; r < 4; ++r) {
                    float u  = fmaf(acc[a][b][r], -2.0f, sqj_l[b]);
                    float d2 = u + sqi4[a][r];
                    bool same = (labi4[a][r] == labj_l[b]);
                    float pv = same ? d2 : -INFINITY;
                    float nv = same ? INFINITY : d2;
                    rowP[a][r] = fmaxf(rowP[a][r], pv);
                    rowN[a][r] = fminf(rowN[a][r], nv);
                    colP[b] = fmaxf(colP[b], pv);
                    colN[b] = fminf(colN[b], nv);
                }
        // reduce col partials across quads, store to colAcc (cols unique per tile)
        #pragma unroll
        for (int b = 0; b < 2; ++b) {
            colP[b] = fmaxf(colP[b], __shfl_xor(colP[b], 16));
            colP[b] = fmaxf(colP[b], __shfl_xor(colP[b], 32));
            colN[b] = fminf(colN[b], __shfl_xor(colN[b], 16));
            colN[b] = fminf(colN[b], __shfl_xor(colN[b], 32));
        }
        if (quad == 0) {
            #pragma unroll
            for (int b = 0; b < 2; ++b) {
                int col = (t << 6) + wx * 32 + b * 16 + lr;
                colP_s[wy * 512 + col] = colP[b];
                colN_s[wy * 512 + col] = colN[b];
            }
        }
    }
    __syncthreads();

    // row write-out: reduce over 16 lr lanes, atomic d^2-bit combine
    #pragma unroll
    for (int a = 0; a < 4; ++a)
        #pragma unroll
        for (int r = 0; r < 4; ++r) {
            float p = rowP[a][r], n = rowN[a][r];
            #pragma unroll
            for (int off = 1; off < 16; off <<= 1) {
                p = fmaxf(p, __shfl_xor(p, off));
                n = fminf(n, __shfl_xor(n, off));
            }
            rowP[a][r] = p; rowN[a][r] = n;
        }
    if (lr == 0) {
        #pragma unroll
        for (int a = 0; a < 4; ++a)
            #pragma unroll
            for (int r = 0; r < 4; ++r) {
                int row = i0 + wy * 64 + a * 16 + quad * 4 + r;
                atomicMax(&ap[row], __float_as_uint(fmaxf(rowP[a][r], 0.f)));  // -inf -> 0: no-op
                atomicMin(&an[row], __float_as_uint(fmaxf(rowN[a][r], 0.f)));  // +inf: no-op
            }
    }
    // col write-out: combine wy halves, skip cols of skipped tiles
    for (int jj = tid; jj < 512; jj += 256) {
        if ((jj >> 6) >= t0) {
            float P = fmaxf(colP_s[jj], colP_s[512 + jj]);
            float Nv = fminf(colN_s[jj], colN_s[512 + jj]);
            atomicMax(&ap[j0 + jj], __float_as_uint(fmaxf(P, 0.f)));
            atomicMin(&an[j0 + jj], __float_as_uint(fmaxf(Nv, 0.f)));
        }
    }
}

// ---------- loss: single block, reads d^2, sqrt here, writes out[0] ----------
__global__ __launch_bounds__(256) void loss_kernel(const float* __restrict__ ap,
                                                   const float* __restrict__ an,
                                                   float* __restrict__ out) {
    int tid = threadIdx.x;
    float sum = 0.f;
    #pragma unroll
    for (int k = 0; k < 8; ++k) {
        int i = k * 1024 + tid * 4;
        f32x4 a4 = *(const f32x4*)&ap[i];
        f32x4 n4 = *(const f32x4*)&an[i];
        #pragma unroll
        for (int c = 0; c < 4; ++c) {
            float apd = __builtin_amdgcn_sqrtf(a4[c]);
            float anv = n4[c];
            float and_ = (anv < INFINITY) ? __builtin_amdgcn_sqrtf(anv) : NEG_FILL;
            sum += fmaxf(0.f, MARGIN_V - (and_ - apd));
        }
    }
    #pragma unroll
    for (int off = 32; off >= 1; off >>= 1) sum += __shfl_xor(sum, off);
    __shared__ float s4[4];
    if ((tid & 63) == 0) s4[tid >> 6] = sum;
    __syncthreads();
    if (tid == 0) out[0] = (s4[0] + s4[1] + s4[2] + s4[3]) * (1.0f / (float)N);
}

extern "C" void kernel_launch(void* const* d_in, const int* in_sizes, int n_in,
                              void* d_out, int out_size, void* d_ws, size_t ws_size,
                              hipStream_t stream) {
    const float* F   = (const float*)d_in[0];
    const int*   lab = (const int*)d_in[1];

    unsigned short* Fb = (unsigned short*)d_ws;          // 2 MB
    float*          sq = (float*)(Fb + (size_t)N * D);   // 32 KB
    unsigned*       ap = (unsigned*)(sq + N);            // 32 KB
    unsigned*       an = ap + N;                         // 32 KB

    convert_kernel<<<N / 4, 256, 0, stream>>>(F, Fb, sq, ap, an);
    gemm_kernel<<<544, 256, 0, stream>>>(Fb, sq, lab, ap, an);
    loss_kernel<<<1, 256, 0, stream>>>((const float*)ap, (const float*)an, (float*)d_out);
}

// Round 9
// 85.876 us; speedup vs baseline: 1.1059x; 1.1059x over previous
//
#include <hip/hip_runtime.h>
#include <hip/hip_bf16.h>
#include <math.h>

#define N 8192
#define D 128
#define MARGIN_V 0.3f
#define NEG_FILL 1000000.0f

typedef short bf16x8 __attribute__((ext_vector_type(8)));
typedef float f32x4  __attribute__((ext_vector_type(4)));

// Fragment-major layout of Fb: frag (g,q) holds rows 16g..16g+15, k 32q..32q+31,
// stored as 64 lanes x 16B: lane L = row (L&15), k-subchunk (L>>4)*8..+7.
// Short index: ((g*4 + q)*64 + L)*8 + j. One layout serves both A and B operands
// of mfma_f32_16x16x32_bf16 (identical operand mappings).

// ---------- convert: F fp32 -> frag-major bf16, sq, init ap/an ----------
__global__ __launch_bounds__(256) void convert_kernel(const float* __restrict__ F,
                                                      unsigned short* __restrict__ Fb,
                                                      float* __restrict__ sq,
                                                      unsigned* __restrict__ ap,
                                                      unsigned* __restrict__ an) {
    __shared__ float red[16][17];
    const int g   = blockIdx.x;          // row group: 16 rows
    const int tid = threadIdx.x;
    const int q = tid >> 6, L = tid & 63;
    const int m = L & 15, j8 = (L >> 4) * 8;

    const float* src = F + (size_t)(16 * g + m) * D + 32 * q + j8;
    float4 v0 = *(const float4*)src;
    float4 v1 = *(const float4*)(src + 4);

    float s = v0.x * v0.x + v0.y * v0.y + v0.z * v0.z + v0.w * v0.w
            + v1.x * v1.x + v1.y * v1.y + v1.z * v1.z + v1.w * v1.w;

    union { bf16x8 v; __hip_bfloat162 h2[4]; } pk;
    pk.h2[0] = __float22bfloat162_rn({v0.x, v0.y});
    pk.h2[1] = __float22bfloat162_rn({v0.z, v0.w});
    pk.h2[2] = __float22bfloat162_rn({v1.x, v1.y});
    pk.h2[3] = __float22bfloat162_rn({v1.z, v1.w});
    *(bf16x8*)&Fb[(size_t)g * 2048 + tid * 8] = pk.v;   // coalesced 4 KB/block

    red[m][q * 4 + (L >> 4)] = s;
    __syncthreads();
    if (tid < 16) {
        float t = 0.f;
        #pragma unroll
        for (int c = 0; c < 16; ++c) t += red[tid][c];
        sq[16 * g + tid] = t;
    }
    int gid = blockIdx.x * 256 + tid;
    if (gid < N) { ap[gid] = 0u; an[gid] = 0x7F800000u; }   // 0.0f / +inf (d^2 domain)
}

// ---------- gemm: zero-LDS, zero-barrier, frag-major global loads ----------
// Block = strip (256 rows, one 64-row sub-strip per wave) x chunk (512 cols).
// 512 blocks = 2/CU. Waves fully independent: A-frags register-cached,
// B-frags double-buffered global->register (coalesced 1KB loads, L1-shared
// across the block's 4 waves). Mining in u = sqj - 2c domain in registers.
__global__ __launch_bounds__(256, 2) void gemm_kernel(const unsigned short* __restrict__ Fb,
                                                      const float* __restrict__ sq,
                                                      const int* __restrict__ lab,
                                                      unsigned* __restrict__ ap,
                                                      unsigned* __restrict__ an) {
    const int tid  = threadIdx.x;
    const int wave = tid >> 6, lane = tid & 63;
    const int quad = lane >> 4, lr = lane & 15;
    const int S = blockIdx.x >> 4;        // strip: 256 rows
    const int C = blockIdx.x & 15;        // chunk: 512 cols
    const int R0   = S * 256 + wave * 64; // this wave's 64 rows
    const int g0   = R0 >> 4;             // row-group base (4 groups)
    const int cg0  = C * 32;              // col-group base (32 groups)
    const int colb = C * 512;

    // A fragments: 4 row-groups x 4 k-chunks, coalesced contiguous loads
    bf16x8 af[4][4];
    #pragma unroll
    for (int a = 0; a < 4; ++a)
        #pragma unroll
        for (int ks = 0; ks < 4; ++ks)
            af[a][ks] = *(const bf16x8*)&Fb[(((size_t)(g0 + a) * 4 + ks) * 64 + lane) * 8];

    f32x4 sqi4[4]; int4 labi4[4];
    #pragma unroll
    for (int a = 0; a < 4; ++a) {
        int base = R0 + a * 16 + quad * 4;
        sqi4[a]  = *(const f32x4*)&sq[base];
        labi4[a] = *(const int4*)&lab[base];
    }

    float rowP[4][4], rowN[4][4];
    #pragma unroll
    for (int a = 0; a < 4; ++a)
        #pragma unroll
        for (int r = 0; r < 4; ++r) { rowP[a][r] = -INFINITY; rowN[a][r] = INFINITY; }

#define LOADT(T, BF, SQJ, LABJ)                                                   \
    {                                                                             \
        _Pragma("unroll")                                                         \
        for (int b = 0; b < 2; ++b) {                                             \
            int gb = cg0 + 2 * (T) + b;                                           \
            _Pragma("unroll")                                                     \
            for (int ks = 0; ks < 4; ++ks)                                        \
                BF[b][ks] = *(const bf16x8*)&Fb[(((size_t)gb * 4 + ks) * 64 + lane) * 8]; \
            SQJ[b]  = sq[colb + (T) * 32 + b * 16 + lr];                          \
            LABJ[b] = lab[colb + (T) * 32 + b * 16 + lr];                         \
        }                                                                         \
    }

#define COMP(BF, SQJ, LABJ)                                                       \
    {                                                                             \
        f32x4 acc[4][2];                                                          \
        _Pragma("unroll")                                                         \
        for (int a = 0; a < 4; ++a)                                               \
            _Pragma("unroll")                                                     \
            for (int b = 0; b < 2; ++b) acc[a][b] = {0.f, 0.f, 0.f, 0.f};         \
        _Pragma("unroll")                                                         \
        for (int ks = 0; ks < 4; ++ks)                                            \
            _Pragma("unroll")                                                     \
            for (int a = 0; a < 4; ++a)                                           \
                _Pragma("unroll")                                                 \
                for (int b = 0; b < 2; ++b)                                       \
                    acc[a][b] = __builtin_amdgcn_mfma_f32_16x16x32_bf16(          \
                        af[a][ks], BF[b][ks], acc[a][b], 0, 0, 0);                \
        _Pragma("unroll")                                                         \
        for (int a = 0; a < 4; ++a)                                               \
            _Pragma("unroll")                                                     \
            for (int b = 0; b < 2; ++b)                                           \
                _Pragma("unroll")                                                 \
                for (int r = 0; r < 4; ++r) {                                     \
                    float u = fmaf(acc[a][b][r], -2.0f, SQJ[b]);                  \
                    bool same = (labi4[a][r] == LABJ[b]);                         \
                    rowP[a][r] = fmaxf(rowP[a][r], same ? u : -INFINITY);         \
                    rowN[a][r] = fminf(rowN[a][r], same ? INFINITY : u);          \
                }                                                                 \
    }

    bf16x8 b0[2][4], b1[2][4];
    float sq0[2], sq1[2];
    int   lb0[2], lb1[2];
    LOADT(0, b0, sq0, lb0);
    #pragma unroll 1
    for (int t = 0; t < 16; t += 2) {
        LOADT(t + 1, b1, sq1, lb1);
        COMP(b0, sq0, lb0);
        if (t + 2 < 16) LOADT(t + 2, b0, sq0, lb0);
        COMP(b1, sq1, lb1);
    }
#undef LOADT
#undef COMP

    // reduce over the 16 lr lanes, add sqi, clamp, atomic d^2-bit combine
    #pragma unroll
    for (int a = 0; a < 4; ++a)
        #pragma unroll
        for (int r = 0; r < 4; ++r) {
            float p = rowP[a][r], n = rowN[a][r];
            #pragma unroll
            for (int off = 1; off < 16; off <<= 1) {
                p = fmaxf(p, __shfl_xor(p, off));
                n = fminf(n, __shfl_xor(n, off));
            }
            rowP[a][r] = p; rowN[a][r] = n;
        }
    if (lr == 0) {
        #pragma unroll
        for (int a = 0; a < 4; ++a)
            #pragma unroll
            for (int r = 0; r < 4; ++r) {
                int row = R0 + a * 16 + quad * 4 + r;
                float pd2 = fmaxf(sqi4[a][r] + rowP[a][r], 0.f);   // -inf -> 0 (no-op vs init)
                float nd2 = fmaxf(sqi4[a][r] + rowN[a][r], 0.f);   // +inf stays +inf (no-op)
                atomicMax(&ap[row], __float_as_uint(pd2));
                atomicMin(&an[row], __float_as_uint(nd2));
            }
    }
}

// ---------- loss: single block, reads d^2, sqrt here, writes out[0] ----------
__global__ __launch_bounds__(256) void loss_kernel(const float* __restrict__ ap,
                                                   const float* __restrict__ an,
                                                   float* __restrict__ out) {
    int tid = threadIdx.x;
    float sum = 0.f;
    #pragma unroll
    for (int k = 0; k < 8; ++k) {
        int i = k * 1024 + tid * 4;
        f32x4 a4 = *(const f32x4*)&ap[i];
        f32x4 n4 = *(const f32x4*)&an[i];
        #pragma unroll
        for (int c = 0; c < 4; ++c) {
            float apd = __builtin_amdgcn_sqrtf(a4[c]);
            float anv = n4[c];
            float and_ = (anv < INFINITY) ? __builtin_amdgcn_sqrtf(anv) : NEG_FILL;
            sum += fmaxf(0.f, MARGIN_V - (and_ - apd));
        }
    }
    #pragma unroll
    for (int off = 32; off >= 1; off >>= 1) sum += __shfl_xor(sum, off);
    __shared__ float s4[4];
    if ((tid & 63) == 0) s4[tid >> 6] = sum;
    __syncthreads();
    if (tid == 0) out[0] = (s4[0] + s4[1] + s4[2] + s4[3]) * (1.0f / (float)N);
}

extern "C" void kernel_launch(void* const* d_in, const int* in_sizes, int n_in,
                              void* d_out, int out_size, void* d_ws, size_t ws_size,
                              hipStream_t stream) {
    const float* F   = (const float*)d_in[0];
    const int*   lab = (const int*)d_in[1];

    unsigned short* Fb = (unsigned short*)d_ws;          // 2 MB, frag-major
    float*          sq = (float*)(Fb + (size_t)N * D);   // 32 KB
    unsigned*       ap = (unsigned*)(sq + N);            // 32 KB
    unsigned*       an = ap + N;                         // 32 KB

    convert_kernel<<<N / 16, 256, 0, stream>>>(F, Fb, sq, ap, an);
    gemm_kernel<<<512, 256, 0, stream>>>(Fb, sq, lab, ap, an);
    loss_kernel<<<1, 256, 0, stream>>>((const float*)ap, (const float*)an, (float*)d_out);
}